// Round 6
// baseline (5158.598 us; speedup 1.0000x reference)
//
#include <hip/hip_runtime.h>
#include <hip/hip_bf16.h>

typedef __attribute__((ext_vector_type(8))) short short8;
typedef __attribute__((ext_vector_type(4))) float f32x4;
typedef unsigned long long u64;

#define V_N 10000
#define D_E 128
#define H_N 512
#define B_N 32
#define S_N 512

// ---- workspace layout (bytes) ----
#define OFF_ARR   0                        // 64 arrive flags, 128-B stride = 8192 B
#define OFF_RP    8192                     // rowpart: 16384 rows x 80 slots f32 = 5,242,880
#define OFF_EMB   (8192 + 5242880)         // S*B*D bf16 = 4,194,304
#define OFF_HS    (OFF_EMB + 4194304)      // S*B*H bf16 = 16,777,216
#define OFF_WOUT  (OFF_HS + 16777216)      // V*H bf16 = 10,240,000

// ------------------------------------------------------------------
__device__ __forceinline__ float ftanh(float x) {
  float e = __expf(-2.f * fabsf(x));          // in (0,1], overflow-safe
  float r = (1.f - e) / (1.f + e);
  return __builtin_copysignf(r, x);
}

// ------------------------------------------------------------------
// prep: embedding gather -> bf16 [s][b][d]
__global__ void k_prep_emb(const int* __restrict__ x, const float* __restrict__ tab,
                           __hip_bfloat16* __restrict__ emb) {
  int i = blockIdx.x * 256 + threadIdx.x;         // over S*B*D = 2,097,152
  if (i >= S_N * B_N * D_E) return;
  int d  = i & (D_E - 1);
  int sb = i >> 7;
  int b  = sb & (B_N - 1);
  int s  = sb >> 5;
  int tok = x[b * S_N + s];
  emb[i] = __float2bfloat16(tab[tok * D_E + d]);
}

// prep: W_out -> bf16
__global__ void k_prep_wout(const float* __restrict__ w, __hip_bfloat16* __restrict__ o) {
  int i = blockIdx.x * 256 + threadIdx.x;
  if (i < V_N * H_N) o[i] = __float2bfloat16(w[i]);
}

// ------------------------------------------------------------------
// persistent recurrence: 64 WGs, WG w owns h-elements j = 8w..8w+7.
// Dataflow version: NO global lockstep barrier. Wave kw's K-slice
// [kw*160, kw*160+160) depends only on producers:
//   wave0: emb + h[0:32)   -> WGs 0..3
//   wave1: h[32:192)       -> WGs 4..23
//   wave2: h[192:352)      -> WGs 24..43
//   wave3: h[352:512)      -> WGs 44..63
// Each wave polls its own producer flags, bypass-loads its own h-slice into
// its PRIVATE Bl region, and MFMAs (no cross-wave Bl sharing). Skew between
// WGs is absorbed: hs[t] slots are unique per t, flags are monotone.
// Publish (store+readback+vmcnt+flag) is done by wave 1 alone.
__launch_bounds__(256, 1)
__global__ void k_recurrence(const int* __restrict__ x,
                             const float* __restrict__ W_ih, const float* __restrict__ W_hh,
                             const float* __restrict__ b_ih, const float* __restrict__ b_hh,
                             const __hip_bfloat16* __restrict__ emb,
                             __hip_bfloat16* __restrict__ hs,     // [512][32][512]
                             unsigned* __restrict__ arrive)       // [64] stride 32 u32
{
  __shared__ __hip_bfloat16 Bl[32][648];   // [example][k] = [emb_t ; h_prev]
  __shared__ float gl4[4][64][33];         // per-wave partial gates
  __shared__ float bias[64];
  __shared__ unsigned short hloc[8][32];   // [jj][b] bf16 bits of new h

  const int tid = threadIdx.x;
  const int wg  = blockIdx.x;              // 0..63
  const int lane = tid & 63, kw = tid >> 6;       // kw = wave = K-slice
  const int lrow = lane & 15, lk = (lane >> 4) * 8;
  const int b_ep = tid & 31, jj_ep = tid >> 5;    // epilogue mapping 32x8

  // ---- one-time: A-fragments (64 rows x K-slice 160) into registers ----
  short8 Afrag[20];                        // [mt*5+ks], 80 VGPRs
  #pragma unroll
  for (int mt = 0; mt < 4; ++mt) {
    #pragma unroll
    for (int ks = 0; ks < 5; ++ks) {
      int lr = mt * 16 + lrow;             // local gate row 0..63
      int q = lr >> 4, kc = (lr >> 3) & 1, jj = lr & 7;
      int grow = kc * 2048 + q * 512 + wg * 8 + jj;
      int c0 = kw * 160 + ks * 32 + lk;
      short8 a;
      #pragma unroll
      for (int e = 0; e < 8; ++e) {
        int c = c0 + e;
        float v = (c < 128) ? W_ih[(size_t)grow * 128 + c]
                            : W_hh[(size_t)grow * 512 + (c - 128)];
        __hip_bfloat16 hb = __float2bfloat16(v);
        a[e] = *(const short*)&hb;
      }
      Afrag[mt * 5 + ks] = a;
    }
  }
  if (tid < 64) {
    int lr = tid;
    int q = lr >> 4, kc = (lr >> 3) & 1, jj = lr & 7;
    int grow = kc * 2048 + q * 512 + wg * 8 + jj;
    bias[lr] = b_ih[grow] + b_hh[grow];
  }

  // ---- per-wave producer flag assignment ----
  const int myf = (kw == 0) ? (lane & 3) : (kw * 20 - 16 + lane % 20);
  const unsigned* afp = arrive + myf * 32;

  // ---- preload token parity bits into registers (b_ep's row of x) ----
  unsigned par[16];
  #pragma unroll
  for (int w = 0; w < 16; ++w) {
    unsigned p = 0;
    for (int bb = 0; bb < 32; ++bb)
      p |= (unsigned)(x[b_ep * S_N + w * 32 + bb] & 1) << bb;
    par[w] = p;
  }

  float c_state = 0.f;                         // carry for (b_ep, j)
  const u64* e64base = (const u64*)emb;

  for (int t = 0; t < S_N; ++t) {
    // ---- per-wave: wait own producers, stage own K-slice of B ----
    if (t == 0) {
      if (kw == 0) {
        #pragma unroll
        for (int it = 0; it < 16; ++it) {       // emb 32x128 = 1024 u64
          int i = it * 64 + lane;
          int ex = i >> 5, wd = i & 31;
          *(u64*)&Bl[ex][wd * 4] = e64base[i];  // t=0
        }
        #pragma unroll
        for (int it = 0; it < 4; ++it) {        // h[0:32) zeros: 256 u64
          int i = it * 64 + lane;
          int ex = i >> 3, wd = i & 7;
          *(u64*)&Bl[ex][128 + wd * 4] = 0ull;
        }
      } else {
        #pragma unroll
        for (int it = 0; it < 20; ++it) {       // 160-col slice zeros: 1280 u64
          int i = it * 64 + lane;
          int ex = i / 40, wd = i - ex * 40;
          *(u64*)&Bl[ex][kw * 160 + wd * 4] = 0ull;
        }
      }
    } else {
      // wait for own producers to have published h(t-1)
      unsigned v;
      do {
        v = __hip_atomic_load(afp, __ATOMIC_RELAXED, __HIP_MEMORY_SCOPE_AGENT);
      } while (!__all((int)(v >= (unsigned)t)));

      const u64* hsrc = (const u64*)hs + (size_t)(t - 1) * 4096;
      if (kw == 0) {
        const u64* e64 = e64base + (size_t)t * 1024;
        #pragma unroll
        for (int it = 0; it < 16; ++it) {       // emb (cached loads)
          int i = it * 64 + lane;
          int ex = i >> 5, wd = i & 31;
          *(u64*)&Bl[ex][wd * 4] = e64[i];
        }
        #pragma unroll
        for (int it = 0; it < 4; ++it) {        // h[0:32): 8 u64/example
          int i = it * 64 + lane;
          int ex = i >> 3, wd = i & 7;
          u64 v8 = __hip_atomic_load(hsrc + ex * 128 + wd,
                                     __ATOMIC_RELAXED, __HIP_MEMORY_SCOPE_AGENT);
          *(u64*)&Bl[ex][128 + wd * 4] = v8;
        }
      } else {
        const int cb64 = (kw * 160 - 128) >> 2;   // u64 offset of h-slice in a row
        #pragma unroll
        for (int it = 0; it < 20; ++it) {       // 160 cols = 40 u64/example
          int i = it * 64 + lane;
          int ex = i / 40, wd = i - ex * 40;
          u64 v8 = __hip_atomic_load(hsrc + ex * 128 + cb64 + wd,
                                     __ATOMIC_RELAXED, __HIP_MEMORY_SCOPE_AGENT);
          *(u64*)&Bl[ex][kw * 160 + wd * 4] = v8;
        }
      }
    }
    asm volatile("" ::: "memory");   // compiler fence: stage before MFMA reads

    // ---- MFMA: wave kw, all 64 rows x 32 cols over its K-slice 160 ----
    {
      f32x4 acc[4][2] = {};
      #pragma unroll
      for (int ks = 0; ks < 5; ++ks) {
        int cb = (kw * 160 + ks * 32 + lk) * 2;    // byte offset in a row
        short8 b0 = *(const short8*)((const char*)&Bl[0][0] + lrow * 1296 + cb);
        short8 b1 = *(const short8*)((const char*)&Bl[0][0] + (16 + lrow) * 1296 + cb);
        #pragma unroll
        for (int mt = 0; mt < 4; ++mt) {
          acc[mt][0] = __builtin_amdgcn_mfma_f32_16x16x32_bf16(Afrag[mt * 5 + ks], b0, acc[mt][0], 0, 0, 0);
          acc[mt][1] = __builtin_amdgcn_mfma_f32_16x16x32_bf16(Afrag[mt * 5 + ks], b1, acc[mt][1], 0, 0, 0);
        }
      }
      #pragma unroll
      for (int mt = 0; mt < 4; ++mt)
        #pragma unroll
        for (int nt = 0; nt < 2; ++nt)
          #pragma unroll
          for (int r = 0; r < 4; ++r)
            gl4[kw][mt * 16 + (lane >> 4) * 4 + r][nt * 16 + (lane & 15)] = acc[mt][nt][r];
    }
    __syncthreads();                 // A: all waves' partials ready

    // ---- epilogue: thread <-> (b_ep, jj_ep); sum 4 K-partials ----
    {
      float cand_c[2], cand_h[2];
      #pragma unroll
      for (int k = 0; k < 2; ++k) {
        int base = k * 8 + jj_ep;
        float ig = gl4[0][base][b_ep] + gl4[1][base][b_ep]
                 + gl4[2][base][b_ep] + gl4[3][base][b_ep] + bias[base];
        float fg = gl4[0][16 + base][b_ep] + gl4[1][16 + base][b_ep]
                 + gl4[2][16 + base][b_ep] + gl4[3][16 + base][b_ep] + bias[16 + base];
        float gg = gl4[0][32 + base][b_ep] + gl4[1][32 + base][b_ep]
                 + gl4[2][32 + base][b_ep] + gl4[3][32 + base][b_ep] + bias[32 + base];
        float og = gl4[0][48 + base][b_ep] + gl4[1][48 + base][b_ep]
                 + gl4[2][48 + base][b_ep] + gl4[3][48 + base][b_ep] + bias[48 + base];
        ig = 1.f / (1.f + __expf(-ig));
        fg = 1.f / (1.f + __expf(-fg));
        og = 1.f / (1.f + __expf(-og));
        gg = ftanh(gg);
        float cn = fg * c_state + ig * gg;
        cand_c[k] = cn;
        cand_h[k] = og * ftanh(cn);
      }
      int sel = (par[t >> 5] >> (t & 31)) & 1;
      c_state  = sel ? cand_c[1] : cand_c[0];
      float hv = sel ? cand_h[1] : cand_h[0];
      __hip_bfloat16 hb = __float2bfloat16(hv);
      hloc[jj_ep][b_ep] = *(const unsigned short*)&hb;
    }
    __syncthreads();                 // B: hloc complete; Bl/gl4 dead -> next step

    // ---- wave 1 alone: publish h(t) + READ-BACK + vmcnt + flag ----
    if (kw == 1) {
      int b = lane >> 1, half = lane & 1;
      u64 v = (u64)hloc[half * 4 + 0][b]
            | ((u64)hloc[half * 4 + 1][b] << 16)
            | ((u64)hloc[half * 4 + 2][b] << 32)
            | ((u64)hloc[half * 4 + 3][b] << 48);
      u64* dst = (u64*)hs + (size_t)t * 4096 + b * 128 + wg * 2 + half;
      __hip_atomic_store(dst, v, __ATOMIC_RELAXED, __HIP_MEMORY_SCOPE_AGENT);
      // read-back proves the line is globally readable at the coherence point
      u64 chk = __hip_atomic_load(dst, __ATOMIC_RELAXED, __HIP_MEMORY_SCOPE_AGENT);
      unsigned c0 = (unsigned)chk, c1 = (unsigned)(chk >> 32);
      asm volatile("" :: "v"(c0), "v"(c1));   // keep live (no DCE)
      asm volatile("s_waitcnt vmcnt(0)" ::: "memory");  // whole wave drained
      if (lane == 0 && t < S_N - 1)
        __hip_atomic_store(arrive + wg * 32, (unsigned)(t + 1),
                           __ATOMIC_RELAXED, __HIP_MEMORY_SCOPE_AGENT);
    }
  }
}

// ------------------------------------------------------------------
// logits GEMM: M=16384 (=S*B), N=10000, K=512, bf16 MFMA, +bias.
// Deterministic fused softmax-denominator: per-block per-row partial
// sum(exp(logit)) -> unique slot rowpart[row][tn] (NO atomics).
__launch_bounds__(256, 2)
__global__ void k_gemm(const __hip_bfloat16* __restrict__ hs,
                       const __hip_bfloat16* __restrict__ wout,
                       const float* __restrict__ b_out,
                       float* __restrict__ out,
                       float* __restrict__ rowpart)   // [16384][80]
{
  __shared__ __hip_bfloat16 Al[128][72];
  __shared__ __hip_bfloat16 Wt[128][72];
  __shared__ float sumLDS[2][128];         // [nq][row_local]
  const int tid = threadIdx.x;
  const int tn = blockIdx.x, tm = blockIdx.y;
  const int lane = tid & 63, wv = tid >> 6;
  const int mq = wv & 1, nq = wv >> 1;
  const int lrow = lane & 15, lk = (lane >> 4) * 8;
  f32x4 acc[4][4] = {};

  const int ar = tid >> 3, ac = (tid & 7) * 8;
  for (int k0 = 0; k0 < 512; k0 += 64) {
    __syncthreads();
    #pragma unroll
    for (int rr = 0; rr < 4; ++rr) {
      int r = ar + rr * 32;
      short8 av = *(const short8*)(hs + ((size_t)(tm * 128 + r)) * 512 + k0 + ac);
      *(short8*)&Al[r][ac] = av;
      int v = tn * 128 + r;
      short8 wvv = {};
      if (v < V_N) wvv = *(const short8*)(wout + (size_t)v * 512 + k0 + ac);
      *(short8*)&Wt[r][ac] = wvv;
    }
    __syncthreads();
    #pragma unroll
    for (int ks = 0; ks < 2; ++ks) {
      int kb = ks * 32 + lk;
      short8 af[4], bf[4];
      #pragma unroll
      for (int i = 0; i < 4; ++i) af[i] = *(const short8*)&Al[mq * 64 + i * 16 + lrow][kb];
      #pragma unroll
      for (int i = 0; i < 4; ++i) bf[i] = *(const short8*)&Wt[nq * 64 + i * 16 + lrow][kb];
      #pragma unroll
      for (int i = 0; i < 4; ++i)
        #pragma unroll
        for (int jx = 0; jx < 4; ++jx)
          acc[i][jx] = __builtin_amdgcn_mfma_f32_16x16x32_bf16(af[i], bf[jx], acc[i][jx], 0, 0, 0);
    }
  }
  const int rbase = tm * 128 + mq * 64 + (lane >> 4) * 4;
  const int cbase = tn * 128 + nq * 64 + (lane & 15);
  float esum[4][4];
  #pragma unroll
  for (int i = 0; i < 4; ++i)
    #pragma unroll
    for (int r = 0; r < 4; ++r) esum[i][r] = 0.f;

  #pragma unroll
  for (int i = 0; i < 4; ++i) {
    #pragma unroll
    for (int jx = 0; jx < 4; ++jx) {
      int col = cbase + jx * 16;
      if (col < V_N) {
        float bo = b_out[col];
        #pragma unroll
        for (int r = 0; r < 4; ++r) {
          int row = rbase + i * 16 + r;
          float lg = acc[i][jx][r] + bo;
          out[(size_t)row * V_N + col] = lg;
          esum[i][r] += __expf(lg);
        }
      }
    }
  }
  // reduce each (i,r) over the 16 lanes of the col group; write LDS partial
  #pragma unroll
  for (int i = 0; i < 4; ++i) {
    #pragma unroll
    for (int r = 0; r < 4; ++r) {
      float s = esum[i][r];
      s += __shfl_xor(s, 1); s += __shfl_xor(s, 2);
      s += __shfl_xor(s, 4); s += __shfl_xor(s, 8);
      if ((lane & 15) == 0)
        sumLDS[nq][mq * 64 + i * 16 + (lane >> 4) * 4 + r] = s;
    }
  }
  __syncthreads();
  if (tid < 128)   // one plain store per (row, tile): deterministic slot
    rowpart[(size_t)(tm * 128 + tid) * 80 + tn] = sumLDS[0][tid] + sumLDS[1][tid];
}

// ------------------------------------------------------------------
// fix-up: lse[r] = log(sum of 79 partials, fixed order); out[r][:] -= lse
__launch_bounds__(256)
__global__ void k_lsm_fix(float* __restrict__ out, const float* __restrict__ rowpart) {
  const int r = blockIdx.x;
  const float* rp = rowpart + (size_t)r * 80;
  float s = 0.f;
  for (int p = 0; p < 79; ++p) s += rp[p];   // same order in every thread/replay
  float lse = __logf(s);
  float4* q4 = (float4*)(out + (size_t)r * V_N);
  for (int i = threadIdx.x; i < V_N / 4; i += 256) {
    float4 v = q4[i];
    v.x -= lse; v.y -= lse; v.z -= lse; v.w -= lse;
    q4[i] = v;
  }
}

// ------------------------------------------------------------------
extern "C" void kernel_launch(void* const* d_in, const int* in_sizes, int n_in,
                              void* d_out, int out_size, void* d_ws, size_t ws_size,
                              hipStream_t stream) {
  const int*   x    = (const int*)d_in[0];
  const float* tab  = (const float*)d_in[1];
  const float* Wih  = (const float*)d_in[2];
  const float* Whh  = (const float*)d_in[3];
  const float* bih  = (const float*)d_in[4];
  const float* bhh  = (const float*)d_in[5];
  const float* Wout = (const float*)d_in[6];
  const float* bout = (const float*)d_in[7];
  float* out = (float*)d_out;

  char* ws = (char*)d_ws;
  unsigned*        arrive  = (unsigned*)(ws + OFF_ARR);
  float*           rowpart = (float*)(ws + OFF_RP);
  __hip_bfloat16*  emb     = (__hip_bfloat16*)(ws + OFF_EMB);
  __hip_bfloat16*  hsbuf   = (__hip_bfloat16*)(ws + OFF_HS);
  __hip_bfloat16*  wob     = (__hip_bfloat16*)(ws + OFF_WOUT);

  hipMemsetAsync(arrive, 0, 8192, stream);
  k_prep_emb<<<(S_N * B_N * D_E) / 256, 256, 0, stream>>>(x, tab, emb);
  k_prep_wout<<<(V_N * H_N) / 256, 256, 0, stream>>>(Wout, wob);
  k_recurrence<<<64, 256, 0, stream>>>(x, Wih, Whh, bih, bhh, emb, hsbuf, arrive);
  k_gemm<<<dim3(79, 128), 256, 0, stream>>>(hsbuf, wob, bout, out, rowpart);
  k_lsm_fix<<<16384, 256, 0, stream>>>(out, rowpart);
}

// Round 7
// 2568.474 us; speedup vs baseline: 2.0084x; 2.0084x over previous
//
#include <hip/hip_runtime.h>
#include <hip/hip_bf16.h>

typedef __attribute__((ext_vector_type(8))) short short8;
typedef __attribute__((ext_vector_type(4))) float f32x4;
typedef unsigned long long u64;

#define V_N 10000
#define D_E 128
#define H_N 512
#define B_N 32
#define S_N 512

#define SENT64 0xFFFFFFFFFFFFFFFFull   // 4x bf16 NaN: unreachable for finite h

// ---- workspace layout (bytes) ----
#define OFF_RP    0                        // rowpart: 16384 rows x 80 slots f32 = 5,242,880
#define OFF_EMB   5242880                  // S*B*D bf16 = 4,194,304
#define OFF_HS    (OFF_EMB + 4194304)      // S*B*H bf16 = 16,777,216
#define OFF_WOUT  (OFF_HS + 16777216)      // V*H bf16 = 10,240,000

// ------------------------------------------------------------------
__device__ __forceinline__ float ftanh(float x) {
  float e = __expf(-2.f * fabsf(x));          // in (0,1], overflow-safe
  float r = (1.f - e) / (1.f + e);
  return __builtin_copysignf(r, x);
}

// ------------------------------------------------------------------
// prep: embedding gather -> bf16 [s][b][d]
__global__ void k_prep_emb(const int* __restrict__ x, const float* __restrict__ tab,
                           __hip_bfloat16* __restrict__ emb) {
  int i = blockIdx.x * 256 + threadIdx.x;         // over S*B*D = 2,097,152
  if (i >= S_N * B_N * D_E) return;
  int d  = i & (D_E - 1);
  int sb = i >> 7;
  int b  = sb & (B_N - 1);
  int s  = sb >> 5;
  int tok = x[b * S_N + s];
  emb[i] = __float2bfloat16(tab[tok * D_E + d]);
}

// prep: W_out -> bf16
__global__ void k_prep_wout(const float* __restrict__ w, __hip_bfloat16* __restrict__ o) {
  int i = blockIdx.x * 256 + threadIdx.x;
  if (i < V_N * H_N) o[i] = __float2bfloat16(w[i]);
}

// ------------------------------------------------------------------
// persistent recurrence: 64 WGs, WG w owns h-elements j = 8w..8w+7.
// Weights (A) in registers; K=640 split across 4 waves (B read once/step).
// Cross-WG exchange: hs[t] slots are WRITE-ONCE; hs is pre-memset to the
// sentinel 0xFF.. (bf16 NaN pattern). Consumers poll the DATA itself with
// bypass loads until != sentinel -> flag+readback+vmcnt chain eliminated;
// publish is fire-and-forget. Values are poll-order independent -> replays
// are bit-identical (memset re-poisons each launch).
__launch_bounds__(256, 1)
__global__ void k_recurrence(const int* __restrict__ x,
                             const float* __restrict__ W_ih, const float* __restrict__ W_hh,
                             const float* __restrict__ b_ih, const float* __restrict__ b_hh,
                             const __hip_bfloat16* __restrict__ emb,
                             __hip_bfloat16* __restrict__ hs)     // [512][32][512]
{
  __shared__ __hip_bfloat16 Bl[32][648];   // [example][k] = [emb_t ; h_prev]
  __shared__ float gl4[4][64][33];         // per-wave partial gates
  __shared__ float bias[64];
  __shared__ unsigned short hloc[8][32];   // [jj][b] bf16 bits of new h

  const int tid = threadIdx.x;
  const int wg  = blockIdx.x;              // 0..63
  const int lane = tid & 63, kw = tid >> 6;       // kw = wave = K-slice
  const int lrow = lane & 15, lk = (lane >> 4) * 8;
  const int b_ep = tid & 31, jj_ep = tid >> 5;    // epilogue mapping 32x8

  // ---- one-time: A-fragments (64 rows x K-slice 160) into registers ----
  short8 Afrag[20];                        // [mt*5+ks], 80 VGPRs
  #pragma unroll
  for (int mt = 0; mt < 4; ++mt) {
    #pragma unroll
    for (int ks = 0; ks < 5; ++ks) {
      int lr = mt * 16 + lrow;             // local gate row 0..63
      int q = lr >> 4, kc = (lr >> 3) & 1, jj = lr & 7;
      int grow = kc * 2048 + q * 512 + wg * 8 + jj;
      int c0 = kw * 160 + ks * 32 + lk;
      short8 a;
      #pragma unroll
      for (int e = 0; e < 8; ++e) {
        int c = c0 + e;
        float v = (c < 128) ? W_ih[(size_t)grow * 128 + c]
                            : W_hh[(size_t)grow * 512 + (c - 128)];
        __hip_bfloat16 hb = __float2bfloat16(v);
        a[e] = *(const short*)&hb;
      }
      Afrag[mt * 5 + ks] = a;
    }
  }
  if (tid < 64) {
    int lr = tid;
    int q = lr >> 4, kc = (lr >> 3) & 1, jj = lr & 7;
    int grow = kc * 2048 + q * 512 + wg * 8 + jj;
    bias[lr] = b_ih[grow] + b_hh[grow];
  }

  // ---- preload token parity bits into registers (b_ep's row of x) ----
  unsigned par[16];
  #pragma unroll
  for (int w = 0; w < 16; ++w) {
    unsigned p = 0;
    for (int bb = 0; bb < 32; ++bb)
      p |= (unsigned)(x[b_ep * S_N + w * 32 + bb] & 1) << bb;
    par[w] = p;
  }

  float c_state = 0.f;                         // carry for (b_ep, j)
  const u64* e64base = (const u64*)emb;

  for (int t = 0; t < S_N; ++t) {
    // ---- stage emb_t (plain cached loads, 8B) ----
    const u64* e64 = e64base + (size_t)t * 1024;   // 32*128 bf16 = 1024 u64
    for (int i = tid; i < 1024; i += 256) {
      int b = i >> 5, dd = i & 31;
      *(u64*)&Bl[b][dd * 4] = e64[i];
    }
    // ---- stage h_prev: batched sentinel-poll on the data itself ----
    if (t == 0) {
      for (int i = tid; i < 4096; i += 256) {
        int b = i >> 7, hh = i & 127;
        *(u64*)&Bl[b][128 + hh * 4] = 0ull;
      }
    } else {
      const u64* src = (const u64*)hs + (size_t)(t - 1) * 4096;
      u64 v0=0,v1=0,v2=0,v3=0,v4=0,v5=0,v6=0,v7=0,
          v8=0,v9=0,v10=0,v11=0,v12=0,v13=0,v14=0,v15=0;
      unsigned pend = 0xFFFFu;
#define POLL1(IT) if (pend & (1u << IT)) \
        v##IT = __hip_atomic_load(src + IT * 256 + tid, __ATOMIC_RELAXED, __HIP_MEMORY_SCOPE_AGENT);
#define COMMIT1(IT) if ((pend & (1u << IT)) && v##IT != SENT64) { \
        int i_ = IT * 256 + tid; \
        *(u64*)&Bl[i_ >> 7][128 + (i_ & 127) * 4] = v##IT; \
        pend &= ~(1u << IT); }
      while (pend) {
        // issue phase: independent loads, pipelined (one RT per sweep)
        POLL1(0) POLL1(1) POLL1(2) POLL1(3) POLL1(4) POLL1(5) POLL1(6) POLL1(7)
        POLL1(8) POLL1(9) POLL1(10) POLL1(11) POLL1(12) POLL1(13) POLL1(14) POLL1(15)
        // commit phase: checks after all loads issued
        COMMIT1(0) COMMIT1(1) COMMIT1(2) COMMIT1(3) COMMIT1(4) COMMIT1(5) COMMIT1(6) COMMIT1(7)
        COMMIT1(8) COMMIT1(9) COMMIT1(10) COMMIT1(11) COMMIT1(12) COMMIT1(13) COMMIT1(14) COMMIT1(15)
      }
#undef POLL1
#undef COMMIT1
    }
    __syncthreads();

    // ---- MFMA: wave kw computes all 64 rows x 32 cols over K-slice 160 ----
    {
      f32x4 acc[4][2] = {};
      #pragma unroll
      for (int ks = 0; ks < 5; ++ks) {
        int cb = (kw * 160 + ks * 32 + lk) * 2;    // byte offset in a row
        short8 b0 = *(const short8*)((const char*)&Bl[0][0] + lrow * 1296 + cb);
        short8 b1 = *(const short8*)((const char*)&Bl[0][0] + (16 + lrow) * 1296 + cb);
        #pragma unroll
        for (int mt = 0; mt < 4; ++mt) {
          acc[mt][0] = __builtin_amdgcn_mfma_f32_16x16x32_bf16(Afrag[mt * 5 + ks], b0, acc[mt][0], 0, 0, 0);
          acc[mt][1] = __builtin_amdgcn_mfma_f32_16x16x32_bf16(Afrag[mt * 5 + ks], b1, acc[mt][1], 0, 0, 0);
        }
      }
      #pragma unroll
      for (int mt = 0; mt < 4; ++mt)
        #pragma unroll
        for (int nt = 0; nt < 2; ++nt)
          #pragma unroll
          for (int r = 0; r < 4; ++r)
            gl4[kw][mt * 16 + (lane >> 4) * 4 + r][nt * 16 + (lane & 15)] = acc[mt][nt][r];
    }
    __syncthreads();

    // ---- epilogue: thread <-> (b_ep, jj_ep); sum 4 K-partials ----
    {
      float cand_c[2], cand_h[2];
      #pragma unroll
      for (int k = 0; k < 2; ++k) {
        int base = k * 8 + jj_ep;
        float ig = gl4[0][base][b_ep] + gl4[1][base][b_ep]
                 + gl4[2][base][b_ep] + gl4[3][base][b_ep] + bias[base];
        float fg = gl4[0][16 + base][b_ep] + gl4[1][16 + base][b_ep]
                 + gl4[2][16 + base][b_ep] + gl4[3][16 + base][b_ep] + bias[16 + base];
        float gg = gl4[0][32 + base][b_ep] + gl4[1][32 + base][b_ep]
                 + gl4[2][32 + base][b_ep] + gl4[3][32 + base][b_ep] + bias[32 + base];
        float og = gl4[0][48 + base][b_ep] + gl4[1][48 + base][b_ep]
                 + gl4[2][48 + base][b_ep] + gl4[3][48 + base][b_ep] + bias[48 + base];
        ig = 1.f / (1.f + __expf(-ig));
        fg = 1.f / (1.f + __expf(-fg));
        og = 1.f / (1.f + __expf(-og));
        gg = ftanh(gg);
        float cn = fg * c_state + ig * gg;
        cand_c[k] = cn;
        cand_h[k] = og * ftanh(cn);
      }
      int sel = (par[t >> 5] >> (t & 31)) & 1;
      c_state  = sel ? cand_c[1] : cand_c[0];
      float hv = sel ? cand_h[1] : cand_h[0];
      __hip_bfloat16 hb = __float2bfloat16(hv);
      hloc[jj_ep][b_ep] = *(const unsigned short*)&hb;
    }
    __syncthreads();

    // ---- publish h(t) into hs[t]: fire-and-forget bypass stores ----
    if (tid < 64) {
      int b = tid >> 1, half = tid & 1;
      u64 v = (u64)hloc[half * 4 + 0][b]
            | ((u64)hloc[half * 4 + 1][b] << 16)
            | ((u64)hloc[half * 4 + 2][b] << 32)
            | ((u64)hloc[half * 4 + 3][b] << 48);
      u64* dst = (u64*)hs + (size_t)t * 4096 + b * 128 + wg * 2 + half;
      __hip_atomic_store(dst, v, __ATOMIC_RELAXED, __HIP_MEMORY_SCOPE_AGENT);
    }
    // no wait, no flag: consumers poll the data itself
  }
}

// ------------------------------------------------------------------
// logits GEMM: M=16384 (=S*B), N=10000, K=512, bf16 MFMA, +bias.
// Deterministic fused softmax-denominator: per-block per-row partial
// sum(exp(logit)) -> unique slot rowpart[row][tn] (NO atomics).
__launch_bounds__(256, 2)
__global__ void k_gemm(const __hip_bfloat16* __restrict__ hs,
                       const __hip_bfloat16* __restrict__ wout,
                       const float* __restrict__ b_out,
                       float* __restrict__ out,
                       float* __restrict__ rowpart)   // [16384][80]
{
  __shared__ __hip_bfloat16 Al[128][72];
  __shared__ __hip_bfloat16 Wt[128][72];
  __shared__ float sumLDS[2][128];         // [nq][row_local]
  const int tid = threadIdx.x;
  const int tn = blockIdx.x, tm = blockIdx.y;
  const int lane = tid & 63, wv = tid >> 6;
  const int mq = wv & 1, nq = wv >> 1;
  const int lrow = lane & 15, lk = (lane >> 4) * 8;
  f32x4 acc[4][4] = {};

  const int ar = tid >> 3, ac = (tid & 7) * 8;
  for (int k0 = 0; k0 < 512; k0 += 64) {
    __syncthreads();
    #pragma unroll
    for (int rr = 0; rr < 4; ++rr) {
      int r = ar + rr * 32;
      short8 av = *(const short8*)(hs + ((size_t)(tm * 128 + r)) * 512 + k0 + ac);
      *(short8*)&Al[r][ac] = av;
      int v = tn * 128 + r;
      short8 wvv = {};
      if (v < V_N) wvv = *(const short8*)(wout + (size_t)v * 512 + k0 + ac);
      *(short8*)&Wt[r][ac] = wvv;
    }
    __syncthreads();
    #pragma unroll
    for (int ks = 0; ks < 2; ++ks) {
      int kb = ks * 32 + lk;
      short8 af[4], bf[4];
      #pragma unroll
      for (int i = 0; i < 4; ++i) af[i] = *(const short8*)&Al[mq * 64 + i * 16 + lrow][kb];
      #pragma unroll
      for (int i = 0; i < 4; ++i) bf[i] = *(const short8*)&Wt[nq * 64 + i * 16 + lrow][kb];
      #pragma unroll
      for (int i = 0; i < 4; ++i)
        #pragma unroll
        for (int jx = 0; jx < 4; ++jx)
          acc[i][jx] = __builtin_amdgcn_mfma_f32_16x16x32_bf16(af[i], bf[jx], acc[i][jx], 0, 0, 0);
    }
  }
  const int rbase = tm * 128 + mq * 64 + (lane >> 4) * 4;
  const int cbase = tn * 128 + nq * 64 + (lane & 15);
  float esum[4][4];
  #pragma unroll
  for (int i = 0; i < 4; ++i)
    #pragma unroll
    for (int r = 0; r < 4; ++r) esum[i][r] = 0.f;

  #pragma unroll
  for (int i = 0; i < 4; ++i) {
    #pragma unroll
    for (int jx = 0; jx < 4; ++jx) {
      int col = cbase + jx * 16;
      if (col < V_N) {
        float bo = b_out[col];
        #pragma unroll
        for (int r = 0; r < 4; ++r) {
          int row = rbase + i * 16 + r;
          float lg = acc[i][jx][r] + bo;
          out[(size_t)row * V_N + col] = lg;
          esum[i][r] += __expf(lg);
        }
      }
    }
  }
  // reduce each (i,r) over the 16 lanes of the col group; write LDS partial
  #pragma unroll
  for (int i = 0; i < 4; ++i) {
    #pragma unroll
    for (int r = 0; r < 4; ++r) {
      float s = esum[i][r];
      s += __shfl_xor(s, 1); s += __shfl_xor(s, 2);
      s += __shfl_xor(s, 4); s += __shfl_xor(s, 8);
      if ((lane & 15) == 0)
        sumLDS[nq][mq * 64 + i * 16 + (lane >> 4) * 4 + r] = s;
    }
  }
  __syncthreads();
  if (tid < 128)   // one plain store per (row, tile): deterministic slot
    rowpart[(size_t)(tm * 128 + tid) * 80 + tn] = sumLDS[0][tid] + sumLDS[1][tid];
}

// ------------------------------------------------------------------
// fix-up: lse[r] = log(sum of 79 partials, fixed order); out[r][:] -= lse
__launch_bounds__(256)
__global__ void k_lsm_fix(float* __restrict__ out, const float* __restrict__ rowpart) {
  const int r = blockIdx.x;
  const float* rp = rowpart + (size_t)r * 80;
  float s = 0.f;
  for (int p = 0; p < 79; ++p) s += rp[p];   // same order in every thread/replay
  float lse = __logf(s);
  float4* q4 = (float4*)(out + (size_t)r * V_N);
  for (int i = threadIdx.x; i < V_N / 4; i += 256) {
    float4 v = q4[i];
    v.x -= lse; v.y -= lse; v.z -= lse; v.w -= lse;
    q4[i] = v;
  }
}

// ------------------------------------------------------------------
extern "C" void kernel_launch(void* const* d_in, const int* in_sizes, int n_in,
                              void* d_out, int out_size, void* d_ws, size_t ws_size,
                              hipStream_t stream) {
  const int*   x    = (const int*)d_in[0];
  const float* tab  = (const float*)d_in[1];
  const float* Wih  = (const float*)d_in[2];
  const float* Whh  = (const float*)d_in[3];
  const float* bih  = (const float*)d_in[4];
  const float* bhh  = (const float*)d_in[5];
  const float* Wout = (const float*)d_in[6];
  const float* bout = (const float*)d_in[7];
  float* out = (float*)d_out;

  char* ws = (char*)d_ws;
  float*           rowpart = (float*)(ws + OFF_RP);
  __hip_bfloat16*  emb     = (__hip_bfloat16*)(ws + OFF_EMB);
  __hip_bfloat16*  hsbuf   = (__hip_bfloat16*)(ws + OFF_HS);
  __hip_bfloat16*  wob     = (__hip_bfloat16*)(ws + OFF_WOUT);

  // re-poison hs to the write-once sentinel every launch (replay-safe)
  hipMemsetAsync(hsbuf, 0xFF, (size_t)S_N * B_N * H_N * 2, stream);
  k_prep_emb<<<(S_N * B_N * D_E) / 256, 256, 0, stream>>>(x, tab, emb);
  k_prep_wout<<<(V_N * H_N) / 256, 256, 0, stream>>>(Wout, wob);
  k_recurrence<<<64, 256, 0, stream>>>(x, Wih, Whh, bih, bhh, emb, hsbuf);
  k_gemm<<<dim3(79, 128), 256, 0, stream>>>(hsbuf, wob, bout, out, rowpart);
  k_lsm_fix<<<16384, 256, 0, stream>>>(out, rowpart);
}